// Round 1
// baseline (308.364 us; speedup 1.0000x reference)
//
#include <hip/hip_runtime.h>
#include <hip/hip_bf16.h>

// Problem constants (match reference)
#define C_CLS 10
#define DIM   3072
#define HID   512
#define LAT   256
#define BATCH 2048
#define BM    64          // GEMM M-tile
#define GRID_TILES 42     // max sum ceil(cnt_c/64) = 32 + 10

typedef __attribute__((ext_vector_type(8))) short  s16x8;
typedef __attribute__((ext_vector_type(4))) short  s16x4;
typedef __attribute__((ext_vector_type(4))) float  f32x4;
typedef __attribute__((ext_vector_type(8))) __bf16 bf16x8;

struct Meta {
    int offsets[C_CLS + 1];
    int ntiles;
    int tileClass[GRID_TILES];
    int tileRow[GRID_TILES];
    int perm[BATCH];        // perm[p] = original row index
};

__device__ __forceinline__ unsigned short f2bf(float f) {
    unsigned u = __builtin_bit_cast(unsigned, f);
    unsigned r = (u + 0x7fffu + ((u >> 16) & 1u)) >> 16;   // RNE
    return (unsigned short)r;
}

__device__ __forceinline__ f32x4 mfma16(s16x8 a, s16x8 b, f32x4 c) {
    return __builtin_amdgcn_mfma_f32_16x16x32_bf16(
        __builtin_bit_cast(bf16x8, a), __builtin_bit_cast(bf16x8, b), c, 0, 0, 0);
}

// ---------------- setup: histogram -> offsets -> tile map -> perm ----------------
__global__ __launch_bounds__(256) void setup_kernel(const int* __restrict__ label,
                                                    Meta* __restrict__ mt,
                                                    float* __restrict__ out) {
    __shared__ int h[C_CLS];
    __shared__ int loff[C_CLS + 1];
    int tid = threadIdx.x;
    if (tid < C_CLS) h[tid] = 0;
    __syncthreads();
    for (int i = tid; i < BATCH; i += 256) atomicAdd(&h[label[i]], 1);
    __syncthreads();
    if (tid == 0) {
        int s = 0, nt = 0;
        for (int c = 0; c < C_CLS; ++c) { loff[c] = s; s += h[c]; }
        loff[C_CLS] = s;
        for (int c = 0; c < C_CLS; ++c) {
            mt->offsets[c] = loff[c];
            int cnt = h[c];
            for (int t = 0; t < cnt; t += BM) {
                mt->tileClass[nt] = c;
                mt->tileRow[nt]   = loff[c] + t;
                ++nt;
            }
            h[c] = loff[c];              // reuse as cursor
        }
        mt->offsets[C_CLS] = loff[C_CLS];
        mt->ntiles = nt;
        out[0] = 0.0f;                   // loss accumulator (d_out poisoned each call)
    }
    __syncthreads();
    for (int i = tid; i < BATCH; i += 256) {
        int pos = atomicAdd(&h[label[i]], 1);
        mt->perm[pos] = i;
    }
}

// ---------------- gather img rows into label-sorted order, f32 -> bf16 ----------------
__global__ __launch_bounds__(256) void gather_kernel(const float* __restrict__ img,
                                                     const Meta* __restrict__ mt,
                                                     unsigned short* __restrict__ Xg) {
    int p    = blockIdx.x;
    int orig = mt->perm[p];
    const float4* src = (const float4*)(img + (size_t)orig * DIM);
    unsigned short* dst = Xg + (size_t)p * DIM;
    for (int j = threadIdx.x; j < DIM / 4; j += 256) {
        float4 v = src[j];
        s16x4 o;
        o.x = (short)f2bf(v.x); o.y = (short)f2bf(v.y);
        o.z = (short)f2bf(v.z); o.w = (short)f2bf(v.w);
        *(s16x4*)(dst + 4 * j) = o;
    }
}

// ---------------- weights: f32 [C][K][N] -> bf16 [C][N][K] (transpose + convert) ----------------
__global__ __launch_bounds__(256) void transpose_cvt(const float* __restrict__ src,
                                                     unsigned short* __restrict__ dst,
                                                     int K, int N) {
    __shared__ unsigned short tile[32][33];
    int c  = blockIdx.z;
    int n0 = blockIdx.x * 32, k0 = blockIdx.y * 32;
    src += (size_t)c * K * N;
    dst += (size_t)c * N * K;
    int tx = threadIdx.x, ty = threadIdx.y;   // 32 x 8
#pragma unroll
    for (int i = 0; i < 4; ++i) {
        int k = k0 + ty + i * 8;
        tile[ty + i * 8][tx] = f2bf(src[(size_t)k * N + n0 + tx]);
    }
    __syncthreads();
#pragma unroll
    for (int i = 0; i < 4; ++i) {
        int n = n0 + ty + i * 8;
        dst[(size_t)n * K + k0 + tx] = tile[tx][ty + i * 8];
    }
}

// ---------------- GEMM: [rows of class c] x W^T, 64x64 tile, bf16 MFMA ----------------
// A:  gathered activations bf16 [BATCH][K]
// Wt: transposed weights   bf16 [C][N][K]
// Swizzle: 16B slot s at row r stored at s ^ (r & 7)  (kills 128B-row bank conflicts)
template <int K, int N, bool RELU, bool FINAL>
__global__ __launch_bounds__(256) void gemm_kernel(const unsigned short* __restrict__ A,
                                                   const unsigned short* __restrict__ Wt,
                                                   const float* __restrict__ bias,
                                                   unsigned short* __restrict__ Aout,
                                                   float* __restrict__ outF,
                                                   const float* __restrict__ img,
                                                   const Meta* __restrict__ mt) {
    int ty = blockIdx.y;
    if (ty >= mt->ntiles) return;
    const int c    = mt->tileClass[ty];
    const int r0   = mt->tileRow[ty];
    const int rend = mt->offsets[c + 1];
    const int n0   = blockIdx.x * 64;

    const unsigned short* W = Wt + ((size_t)c * N + n0) * K;

    __shared__ __align__(16) unsigned short As[64 * 64];
    __shared__ __align__(16) unsigned short Bs[64 * 64];

    const int tid  = threadIdx.x;
    const int lane = tid & 63;
    const int wid  = tid >> 6;
    const int wm   = wid >> 1, wn = wid & 1;   // 2x2 wave grid, 32x32 each

    f32x4 acc[2][2] = {};

    for (int k0 = 0; k0 < K; k0 += 64) {
        // ---- stage 64x64 A and B tiles (reg -> swizzled LDS) ----
#pragma unroll
        for (int h = 0; h < 2; ++h) {
            int ch   = tid + h * 256;          // 512 chunks of 16B per tile
            int row  = ch >> 3;
            int slot = ch & 7;
            int ss   = slot ^ (row & 7);
            int arow = min(r0 + row, rend - 1);              // clamp partial tile
            s16x8 av = *(const s16x8*)(A + (size_t)arow * K + k0 + slot * 8);
            s16x8 bv = *(const s16x8*)(W + (size_t)row * K + k0 + slot * 8);
            *(s16x8*)(As + row * 64 + ss * 8) = av;
            *(s16x8*)(Bs + row * 64 + ss * 8) = bv;
        }
        __syncthreads();
        // ---- compute: 2 k-substeps x (2m x 2n) MFMAs ----
#pragma unroll
        for (int ks = 0; ks < 2; ++ks) {
            int kslot = ks * 4 + (lane >> 4);
            int rA0 = wm * 32 + (lane & 15), rA1 = rA0 + 16;
            int rB0 = wn * 32 + (lane & 15), rB1 = rB0 + 16;
            s16x8 a0 = *(const s16x8*)(As + rA0 * 64 + (kslot ^ (rA0 & 7)) * 8);
            s16x8 a1 = *(const s16x8*)(As + rA1 * 64 + (kslot ^ (rA1 & 7)) * 8);
            s16x8 b0 = *(const s16x8*)(Bs + rB0 * 64 + (kslot ^ (rB0 & 7)) * 8);
            s16x8 b1 = *(const s16x8*)(Bs + rB1 * 64 + (kslot ^ (rB1 & 7)) * 8);
            acc[0][0] = mfma16(a0, b0, acc[0][0]);
            acc[0][1] = mfma16(a0, b1, acc[0][1]);
            acc[1][0] = mfma16(a1, b0, acc[1][0]);
            acc[1][1] = mfma16(a1, b1, acc[1][1]);
        }
        __syncthreads();
    }

    // ---- epilogue.  C/D layout: col = lane&15, row = (lane>>4)*4 + reg ----
    const int col = lane & 15;
    const int rq  = lane >> 4;
    if constexpr (!FINAL) {
#pragma unroll
        for (int mi = 0; mi < 2; ++mi)
#pragma unroll
            for (int ni = 0; ni < 2; ++ni) {
                int n   = n0 + wn * 32 + ni * 16 + col;
                float bv = bias[(size_t)c * N + n];
#pragma unroll
                for (int r = 0; r < 4; ++r) {
                    int m = r0 + wm * 32 + mi * 16 + rq * 4 + r;
                    if (m < rend) {
                        float v = acc[mi][ni][r] + bv;
                        if (RELU) v = fmaxf(v, 0.0f);
                        Aout[(size_t)m * N + n] = f2bf(v);
                    }
                }
            }
    } else {
        float lsum = 0.0f;
#pragma unroll
        for (int mi = 0; mi < 2; ++mi) {
#pragma unroll
            for (int r = 0; r < 4; ++r) {
                int m = r0 + wm * 32 + mi * 16 + rq * 4 + r;
                if (m < rend) {
                    int orig = mt->perm[m];
#pragma unroll
                    for (int ni = 0; ni < 2; ++ni) {
                        int n   = n0 + wn * 32 + ni * 16 + col;
                        float v = acc[mi][ni][r] + bias[(size_t)c * N + n];
                        size_t idx = (size_t)orig * N + n;
                        outF[1 + idx] = v;
                        float d = v - img[idx];
                        lsum += d * d;
                    }
                }
            }
        }
        // block-reduce lsum, one atomic per block, pre-scaled by 1/(B*D)
#pragma unroll
        for (int o = 32; o > 0; o >>= 1) lsum += __shfl_down(lsum, o);
        __shared__ float red[4];
        if (lane == 0) red[wid] = lsum;
        __syncthreads();
        if (tid == 0)
            atomicAdd(&outF[0],
                      (red[0] + red[1] + red[2] + red[3]) * (1.0f / ((float)BATCH * (float)DIM)));
    }
}

// ---------------- launch ----------------
extern "C" void kernel_launch(void* const* d_in, const int* in_sizes, int n_in,
                              void* d_out, int out_size, void* d_ws, size_t ws_size,
                              hipStream_t stream) {
    const float* img    = (const float*)d_in[0];
    const int*   label  = (const int*)d_in[1];
    const float* enc_w1 = (const float*)d_in[2];
    const float* enc_b1 = (const float*)d_in[3];
    const float* enc_w2 = (const float*)d_in[4];
    const float* enc_b2 = (const float*)d_in[5];
    const float* dec_w1 = (const float*)d_in[6];
    const float* dec_b1 = (const float*)d_in[7];
    const float* dec_w2 = (const float*)d_in[8];
    const float* dec_b2 = (const float*)d_in[9];
    float* out = (float*)d_out;

    auto alignup = [](size_t x) { return (x + 255) & ~(size_t)255; };
    char* p = (char*)d_ws;
    size_t off = 0;
    Meta* meta = (Meta*)p;                         off += alignup(sizeof(Meta));
    unsigned short* Wt1 = (unsigned short*)(p + off); off += alignup((size_t)C_CLS * HID * DIM * 2);
    unsigned short* Wt2 = (unsigned short*)(p + off); off += alignup((size_t)C_CLS * LAT * HID * 2);
    unsigned short* Wt3 = (unsigned short*)(p + off); off += alignup((size_t)C_CLS * HID * LAT * 2);
    unsigned short* Wt4 = (unsigned short*)(p + off); off += alignup((size_t)C_CLS * DIM * HID * 2);
    unsigned short* Xg  = (unsigned short*)(p + off); off += alignup((size_t)BATCH * DIM * 2);
    unsigned short* H1  = (unsigned short*)(p + off); off += alignup((size_t)BATCH * HID * 2);
    unsigned short* Z1  = (unsigned short*)(p + off); off += alignup((size_t)BATCH * LAT * 2);
    unsigned short* H2  = (unsigned short*)(p + off); off += alignup((size_t)BATCH * HID * 2);
    (void)ws_size; (void)in_sizes; (void)n_in; (void)out_size;

    setup_kernel<<<1, 256, 0, stream>>>(label, meta, out);
    gather_kernel<<<BATCH, 256, 0, stream>>>(img, meta, Xg);

    transpose_cvt<<<dim3(HID / 32, DIM / 32, C_CLS), dim3(32, 8), 0, stream>>>(enc_w1, Wt1, DIM, HID);
    transpose_cvt<<<dim3(LAT / 32, HID / 32, C_CLS), dim3(32, 8), 0, stream>>>(enc_w2, Wt2, HID, LAT);
    transpose_cvt<<<dim3(HID / 32, LAT / 32, C_CLS), dim3(32, 8), 0, stream>>>(dec_w1, Wt3, LAT, HID);
    transpose_cvt<<<dim3(DIM / 32, HID / 32, C_CLS), dim3(32, 8), 0, stream>>>(dec_w2, Wt4, HID, DIM);

    gemm_kernel<DIM, HID, true,  false><<<dim3(HID / 64, GRID_TILES), 256, 0, stream>>>(
        Xg, Wt1, enc_b1, H1, nullptr, nullptr, meta);
    gemm_kernel<HID, LAT, false, false><<<dim3(LAT / 64, GRID_TILES), 256, 0, stream>>>(
        H1, Wt2, enc_b2, Z1, nullptr, nullptr, meta);
    gemm_kernel<LAT, HID, true,  false><<<dim3(HID / 64, GRID_TILES), 256, 0, stream>>>(
        Z1, Wt3, dec_b1, H2, nullptr, nullptr, meta);
    gemm_kernel<HID, DIM, false, true ><<<dim3(DIM / 64, GRID_TILES), 256, 0, stream>>>(
        H2, Wt4, dec_b2, nullptr, out, img, meta);
}

// Round 4
// 296.379 us; speedup vs baseline: 1.0404x; 1.0404x over previous
//
#include <hip/hip_runtime.h>
#include <hip/hip_bf16.h>

// Problem constants (match reference)
#define C_CLS 10
#define DIM   3072
#define HID   512
#define LAT   256
#define BATCH 2048
#define BM    64          // GEMM M-tile
#define GRID_TILES 42     // max sum ceil(cnt_c/64) = 32 + 10

typedef __attribute__((ext_vector_type(8))) short  s16x8;
typedef __attribute__((ext_vector_type(4))) float  f32x4;
typedef __attribute__((ext_vector_type(8))) __bf16 bf16x8;

struct Meta {
    int offsets[C_CLS + 1];
    int ntiles;
    int tileClass[GRID_TILES];
    int tileRow[GRID_TILES];
    int perm[BATCH];        // perm[p] = original row index
};

__device__ __forceinline__ unsigned short f2bf(float f) {
    unsigned u = __builtin_bit_cast(unsigned, f);
    unsigned r = (u + 0x7fffu + ((u >> 16) & 1u)) >> 16;   // RNE
    return (unsigned short)r;
}

__device__ __forceinline__ f32x4 mfma16(s16x8 a, s16x8 b, f32x4 c) {
    return __builtin_amdgcn_mfma_f32_16x16x32_bf16(
        __builtin_bit_cast(bf16x8, a), __builtin_bit_cast(bf16x8, b), c, 0, 0, 0);
}

// ---------------- setup: histogram -> offsets -> tile map -> perm ----------------
__global__ __launch_bounds__(256) void setup_kernel(const int* __restrict__ label,
                                                    Meta* __restrict__ mt,
                                                    float* __restrict__ out) {
    __shared__ int h[C_CLS];
    __shared__ int loff[C_CLS + 1];
    int tid = threadIdx.x;
    if (tid < C_CLS) h[tid] = 0;
    __syncthreads();
    for (int i = tid; i < BATCH; i += 256) atomicAdd(&h[label[i]], 1);
    __syncthreads();
    if (tid == 0) {
        int s = 0, nt = 0;
        for (int c = 0; c < C_CLS; ++c) { loff[c] = s; s += h[c]; }
        loff[C_CLS] = s;
        for (int c = 0; c < C_CLS; ++c) {
            mt->offsets[c] = loff[c];
            int cnt = h[c];
            for (int t = 0; t < cnt; t += BM) {
                mt->tileClass[nt] = c;
                mt->tileRow[nt]   = loff[c] + t;
                ++nt;
            }
            h[c] = loff[c];              // reuse as cursor
        }
        mt->offsets[C_CLS] = loff[C_CLS];
        mt->ntiles = nt;
        out[0] = 0.0f;                   // loss accumulator (d_out poisoned each call)
    }
    __syncthreads();
    for (int i = tid; i < BATCH; i += 256) {
        int pos = atomicAdd(&h[label[i]], 1);
        mt->perm[pos] = i;
    }
}

// ---------------- fused GEMM ----------------
// A (activations): GATHER ? f32 img rows gathered via perm : bf16 [BATCH][K]
// B (weights)    : f32 [C][K][N] read directly; transposed+converted during LDS staging
// 64x64 tile, BK=64, 2x2 waves of 32x32, double-buffered LDS, 2-phase pipeline.
// LDS swizzle: 16B k-slot s of row r stored at slot s ^ (r & 7)  (conflict-free b128 reads)
template <int K, int N, bool RELU, bool FINAL, bool GATHER>
__global__ __launch_bounds__(256) void gemm_kernel(const void* __restrict__ Ain,
                                                   const float* __restrict__ W,
                                                   const float* __restrict__ bias,
                                                   unsigned short* __restrict__ Aout,
                                                   float* __restrict__ outF,
                                                   const float* __restrict__ img,
                                                   const Meta* __restrict__ mt) {
    int ty = blockIdx.y;
    if (ty >= mt->ntiles) return;
    const int c    = mt->tileClass[ty];
    const int r0   = mt->tileRow[ty];
    const int rend = mt->offsets[c + 1];
    const int n0   = blockIdx.x * 64;

    const float* Wc = W + (size_t)c * K * N + n0;   // element (k, nl) at Wc[k*N + nl]

    __shared__ __align__(16) unsigned short As[2][64 * 64];
    __shared__ __align__(16) unsigned short Bs[2][64 * 64];

    const int tid  = threadIdx.x;
    const int lane = tid & 63;
    const int wid  = tid >> 6;
    const int wm   = wid >> 1, wn = wid & 1;   // 2x2 wave grid, 32x32 each

    // staging roles
    const int aRow0 = tid >> 3;                // A chunk 0 row (chunk 1 row = +32)
    const int aSlot = tid & 7;                 // 16B k-slot within row
    const int bO    = tid >> 5;                // B k-octet 0..7
    const int bN2   = tid & 31;                // B n-pair 0..31

    // in-flight staging registers
    float4 ga[4];          // GATHER A path (2 chunks x 2 float4)
    s16x8  aa[2];          // bf16 A path
    float2 bb[8];          // B: 8 k-rows x 2 n

    auto load_tile = [&](int k0) {
#pragma unroll
        for (int h = 0; h < 2; ++h) {
            int row = aRow0 + h * 32;
            int ar  = min(r0 + row, rend - 1);           // clamp partial tile
            if constexpr (GATHER) {
                int orig = mt->perm[ar];
                const float* src = (const float*)Ain + (size_t)orig * K + k0 + aSlot * 8;
                ga[2 * h]     = *(const float4*)(src);
                ga[2 * h + 1] = *(const float4*)(src + 4);
            } else {
                aa[h] = *(const s16x8*)((const unsigned short*)Ain + (size_t)ar * K + k0 + aSlot * 8);
            }
        }
        const float* src = Wc + (size_t)(k0 + 8 * bO) * N + 2 * bN2;
#pragma unroll
        for (int i = 0; i < 8; ++i) bb[i] = *(const float2*)(src + (size_t)i * N);
    };

    auto write_tile = [&](int buf) {
#pragma unroll
        for (int h = 0; h < 2; ++h) {
            int row = aRow0 + h * 32;
            s16x8 v;
            if constexpr (GATHER) {
#pragma unroll
                for (int j = 0; j < 4; ++j) {
                    ((unsigned short*)&v)[j]     = f2bf(((const float*)&ga[2 * h])[j]);
                    ((unsigned short*)&v)[4 + j] = f2bf(((const float*)&ga[2 * h + 1])[j]);
                }
            } else {
                v = aa[h];
            }
            *(s16x8*)(&As[buf][row * 64 + ((aSlot ^ (row & 7))) * 8]) = v;
        }
#pragma unroll
        for (int nn = 0; nn < 2; ++nn) {
            int n = 2 * bN2 + nn;
            s16x8 v;
#pragma unroll
            for (int i = 0; i < 8; ++i)
                ((unsigned short*)&v)[i] = f2bf(nn ? bb[i].y : bb[i].x);
            *(s16x8*)(&Bs[buf][n * 64 + ((bO ^ (n & 7))) * 8]) = v;
        }
    };

    f32x4 acc[2][2] = {};
    constexpr int NT = K / 64;

    load_tile(0);
    write_tile(0);
    __syncthreads();

    for (int t = 0; t < NT; ++t) {
        int cur = t & 1;
        if (t + 1 < NT) load_tile((t + 1) * 64);   // issue next-tile loads before compute
#pragma unroll
        for (int ks = 0; ks < 2; ++ks) {
            int kslot = ks * 4 + (lane >> 4);
            int rA0 = wm * 32 + (lane & 15), rA1 = rA0 + 16;
            int rB0 = wn * 32 + (lane & 15), rB1 = rB0 + 16;
            s16x8 a0 = *(const s16x8*)(&As[cur][rA0 * 64 + (kslot ^ (rA0 & 7)) * 8]);
            s16x8 a1 = *(const s16x8*)(&As[cur][rA1 * 64 + (kslot ^ (rA1 & 7)) * 8]);
            s16x8 b0 = *(const s16x8*)(&Bs[cur][rB0 * 64 + (kslot ^ (rB0 & 7)) * 8]);
            s16x8 b1 = *(const s16x8*)(&Bs[cur][rB1 * 64 + (kslot ^ (rB1 & 7)) * 8]);
            acc[0][0] = mfma16(a0, b0, acc[0][0]);
            acc[0][1] = mfma16(a0, b1, acc[0][1]);
            acc[1][0] = mfma16(a1, b0, acc[1][0]);
            acc[1][1] = mfma16(a1, b1, acc[1][1]);
        }
        if (t + 1 < NT) write_tile(cur ^ 1);       // fill other buffer; readers of it are past
        __syncthreads();
    }

    // ---- epilogue.  C/D layout: col = lane&15, row = (lane>>4)*4 + reg ----
    const int col = lane & 15;
    const int rq  = lane >> 4;
    if constexpr (!FINAL) {
#pragma unroll
        for (int mi = 0; mi < 2; ++mi)
#pragma unroll
            for (int ni = 0; ni < 2; ++ni) {
                int n    = n0 + wn * 32 + ni * 16 + col;
                float bv = bias[(size_t)c * N + n];
#pragma unroll
                for (int r = 0; r < 4; ++r) {
                    int m = r0 + wm * 32 + mi * 16 + rq * 4 + r;
                    if (m < rend) {
                        float v = acc[mi][ni][r] + bv;
                        if (RELU) v = fmaxf(v, 0.0f);
                        Aout[(size_t)m * N + n] = f2bf(v);
                    }
                }
            }
    } else {
        float lsum = 0.0f;
#pragma unroll
        for (int mi = 0; mi < 2; ++mi) {
#pragma unroll
            for (int r = 0; r < 4; ++r) {
                int m = r0 + wm * 32 + mi * 16 + rq * 4 + r;
                if (m < rend) {
                    int orig = mt->perm[m];
#pragma unroll
                    for (int ni = 0; ni < 2; ++ni) {
                        int n   = n0 + wn * 32 + ni * 16 + col;
                        float v = acc[mi][ni][r] + bias[(size_t)c * N + n];
                        size_t idx = (size_t)orig * N + n;
                        outF[1 + idx] = v;
                        float d = v - img[idx];
                        lsum += d * d;
                    }
                }
            }
        }
#pragma unroll
        for (int o = 32; o > 0; o >>= 1) lsum += __shfl_down(lsum, o);
        __shared__ float red[4];
        if (lane == 0) red[wid] = lsum;
        __syncthreads();
        if (tid == 0)
            atomicAdd(&outF[0],
                      (red[0] + red[1] + red[2] + red[3]) * (1.0f / ((float)BATCH * (float)DIM)));
    }
}

// ---------------- launch ----------------
extern "C" void kernel_launch(void* const* d_in, const int* in_sizes, int n_in,
                              void* d_out, int out_size, void* d_ws, size_t ws_size,
                              hipStream_t stream) {
    const float* img    = (const float*)d_in[0];
    const int*   label  = (const int*)d_in[1];
    const float* enc_w1 = (const float*)d_in[2];
    const float* enc_b1 = (const float*)d_in[3];
    const float* enc_w2 = (const float*)d_in[4];
    const float* enc_b2 = (const float*)d_in[5];
    const float* dec_w1 = (const float*)d_in[6];
    const float* dec_b1 = (const float*)d_in[7];
    const float* dec_w2 = (const float*)d_in[8];
    const float* dec_b2 = (const float*)d_in[9];
    float* out = (float*)d_out;

    auto alignup = [](size_t x) { return (x + 255) & ~(size_t)255; };
    char* p = (char*)d_ws;
    size_t off = 0;
    Meta* meta = (Meta*)p;                            off += alignup(sizeof(Meta));
    unsigned short* H1 = (unsigned short*)(p + off);  off += alignup((size_t)BATCH * HID * 2);
    unsigned short* Z1 = (unsigned short*)(p + off);  off += alignup((size_t)BATCH * LAT * 2);
    unsigned short* H2 = (unsigned short*)(p + off);  off += alignup((size_t)BATCH * HID * 2);
    (void)ws_size; (void)in_sizes; (void)n_in; (void)out_size;

    setup_kernel<<<1, 256, 0, stream>>>(label, meta, out);

    gemm_kernel<DIM, HID, true,  false, true ><<<dim3(HID / 64, GRID_TILES), 256, 0, stream>>>(
        img, enc_w1, enc_b1, H1, nullptr, nullptr, meta);
    gemm_kernel<HID, LAT, false, false, false><<<dim3(LAT / 64, GRID_TILES), 256, 0, stream>>>(
        H1, enc_w2, enc_b2, Z1, nullptr, nullptr, meta);
    gemm_kernel<LAT, HID, true,  false, false><<<dim3(HID / 64, GRID_TILES), 256, 0, stream>>>(
        Z1, dec_w1, dec_b1, H2, nullptr, nullptr, meta);
    gemm_kernel<HID, DIM, false, true,  false><<<dim3(DIM / 64, GRID_TILES), 256, 0, stream>>>(
        H2, dec_w2, dec_b2, nullptr, out, img, meta);
}